// Round 10
// baseline (1247.892 us; speedup 1.0000x reference)
//
#include <hip/hip_runtime.h>
#include <math.h>

#define BB 1024
#define TT 512
#define BC 512   // layer-1 batch chunk

typedef __attribute__((ext_vector_type(8))) short  short8;
typedef __attribute__((ext_vector_type(4))) float  floatx4;

__device__ __forceinline__ float fast_rcp(float x){ return __builtin_amdgcn_rcpf(x); }
__device__ __forceinline__ float sigmoidf_(float x){ return fast_rcp(1.0f + __expf(-x)); }
__device__ __forceinline__ float tanhf_(float x){
    float t = __expf(2.0f * x);
    return 1.0f - 2.0f * fast_rcp(t + 1.0f);
}
__device__ __forceinline__ unsigned short f2bf(float f){
    unsigned u = __builtin_bit_cast(unsigned, f);
    u += 0x7fffu + ((u >> 16) & 1u);
    return (unsigned short)(u >> 16);
}
__device__ __forceinline__ float bf2f(unsigned short u){
    return __builtin_bit_cast(float, ((unsigned)u) << 16);
}

// one-shot bf16 conversion of w_ih_l1 (graph-safe: idempotent, runs every call)
__global__ void wcvt(const float* __restrict__ w, unsigned short* __restrict__ o, int n){
    int idx = blockIdx.x*256 + threadIdx.x;
    if (idx < n) o[idx] = f2bf(w[idx]);
}

// ---------------------------------------------------------------------------
// Layer 0 recurrence, fused tiny projection. 1 wave = one (b,d) sequence.
// lane = i + 32*half; recurrent dot k-split (wh: 48 VGPR), x-projection
// half-split: half0 computes r,z x-dots, half1 computes n x-dot; all four
// partial sums reduced with one shfl_xor(32) each. Natural VGPR ~98 < the
// ~128 remat threshold (R4-R8 matrix) -> weights stay register-resident.
// ---------------------------------------------------------------------------
__global__ __launch_bounds__(64, 2) void gru_l0(
    const float* __restrict__ x,      // (B,T,4)
    const float* __restrict__ w_ih,   // (2,96,4)
    const float* __restrict__ w_hh,   // (2,96,32)
    const float* __restrict__ b_ih,   // (2,96)
    const float* __restrict__ b_hh,   // (2,96)
    unsigned short* __restrict__ h1)  // (B,T,64) bf16
{
    const int b    = blockIdx.x >> 1;
    const int d    = blockIdx.x & 1;
    const int lane = threadIdx.x;
    const int i    = lane & 31;
    const int half = lane >> 5;

    float4 wh[3][4];
    #pragma unroll
    for (int g = 0; g < 3; ++g)
        #pragma unroll
        for (int k = 0; k < 4; ++k)
            wh[g][k] = *(const float4*)(w_hh + (size_t)(d*96 + g*32 + i)*32 + half*16 + k*4);

    // x-projection rows: half0 -> (r_i, z_i); half1 -> (n_i, zero)
    float4 wiA = *(const float4*)(w_ih + (size_t)(d*96 + (half ? 64 : 0) + i)*4);
    float4 wiB = {0.f,0.f,0.f,0.f};
    if (!half) wiB = *(const float4*)(w_ih + (size_t)(d*96 + 32 + i)*4);

    const float bxr = b_ih[d*96 + i]      + b_hh[d*96 + i];
    const float bxz = b_ih[d*96 + 32 + i] + b_hh[d*96 + 32 + i];
    const float bxn = b_ih[d*96 + 64 + i];
    const float bhn = b_hh[d*96 + 64 + i];

    __shared__ __align__(16) float h_sh[32];
    if (!half) h_sh[i] = 0.0f;
    float h = 0.0f;

    const size_t xbase = (size_t)b * TT;
    float4 xc = *(const float4*)(x + (xbase + (d ? TT-1 : 0))*4);

    for (int t = 0; t < TT; ++t) {
        const int tx = d ? (TT-1-t) : t;
        float4 xn4 = xc;
        if (t+1 < TT)
            xn4 = *(const float4*)(x + (xbase + (d ? TT-2-t : t+1))*4);

        const float pA = xc.x*wiA.x + xc.y*wiA.y + xc.z*wiA.z + xc.w*wiA.w;
        const float pB = xc.x*wiB.x + xc.y*wiB.y + xc.z*wiB.z + xc.w*wiB.w;

        float hr_ = 0.f, hz_ = 0.f, hn_ = 0.f;
        #pragma unroll
        for (int k = 0; k < 4; ++k) {
            const float4 hv = *(const float4*)&h_sh[half*16 + k*4];  // broadcast
            hr_ += hv.x*wh[0][k].x + hv.y*wh[0][k].y + hv.z*wh[0][k].z + hv.w*wh[0][k].w;
            hz_ += hv.x*wh[1][k].x + hv.y*wh[1][k].y + hv.z*wh[1][k].z + hv.w*wh[1][k].w;
            hn_ += hv.x*wh[2][k].x + hv.y*wh[2][k].y + hv.z*wh[2][k].z + hv.w*wh[2][k].w;
        }
        float sr = hr_ + (half ? 0.f : pA);
        float sz = hz_ + pB;                // pB==0 in half1
        float sn = hn_;
        float sx = half ? pA : 0.f;
        sr += __shfl_xor(sr, 32, 64);
        sz += __shfl_xor(sz, 32, 64);
        sn += __shfl_xor(sn, 32, 64);
        sx += __shfl_xor(sx, 32, 64);

        const float r = sigmoidf_(sr + bxr);
        const float z = sigmoidf_(sz + bxz);
        const float n = tanhf_(sx + bxn + r*(sn + bhn));
        h = n + z*(h - n);
        if (!half) {
            h_sh[i] = h;
            h1[(xbase + tx)*64 + d*32 + i] = f2bf(h);
        }
        xc = xn4;
    }
}

// ---------------------------------------------------------------------------
// Layer-1 input projection as parallel MFMA GEMM (per batch chunk):
// xg[b,d,t,96] = h1[b,t,0:64] @ w_ih1[d]^T   (no bias — added in gru_l1).
// Wave = 16 t-rows of one b; 12 gate-tiles x 2 k-tiles of 16x16x32 bf16.
// ---------------------------------------------------------------------------
__global__ __launch_bounds__(64, 1) void xg1_pass(
    const unsigned short* __restrict__ h1,   // (B,T,64) bf16
    const unsigned short* __restrict__ wbf,  // (2,96,64) bf16
    unsigned short* __restrict__ xg,         // (BC,2,T,96) bf16
    int b0)
{
    const int blk  = blockIdx.x;           // [0, BC*TT/16)
    const int bl   = blk >> 5;             // TT/16 = 32 tiles per b
    const int t0   = (blk & 31) << 4;
    const int L    = threadIdx.x;
    const int col  = L & 15;
    const int quad = L >> 4;

    const size_t hrow = ((size_t)(b0 + bl)*TT + t0 + col)*64;
    const short8 a0 = *(const short8*)(&h1[hrow +      quad*8]);
    const short8 a1 = *(const short8*)(&h1[hrow + 32 + quad*8]);

    const floatx4 z4 = {0.f,0.f,0.f,0.f};
    #pragma unroll
    for (int nt = 0; nt < 12; ++nt){
        const int dd = nt / 6, gb = nt % 6;
        const size_t row = (size_t)(dd*96 + gb*16 + col)*64;
        const short8 w0 = *(const short8*)(&wbf[row +      quad*8]);
        const short8 w1 = *(const short8*)(&wbf[row + 32 + quad*8]);
        floatx4 acc = __builtin_amdgcn_mfma_f32_16x16x32_bf16(a0, w0, z4, 0, 0, 0);
        acc         = __builtin_amdgcn_mfma_f32_16x16x32_bf16(a1, w1, acc, 0, 0, 0);
        #pragma unroll
        for (int reg = 0; reg < 4; ++reg)
            xg[((size_t)(bl*2 + dd)*TT + t0 + quad*4 + reg)*96 + gb*16 + col] = f2bf(acc[reg]);
    }
}

// ---------------------------------------------------------------------------
// Layer 1 recurrence: like gru_l0 but projection comes from precomputed xg.
// Only w_hh resident (48 VGPR) -> natural pressure ~85, well under threshold.
// ---------------------------------------------------------------------------
__global__ __launch_bounds__(64, 2) void gru_l1(
    const unsigned short* __restrict__ xg,   // (BC,2,T,96) bf16
    const float* __restrict__ w_hh,          // (2,96,32)
    const float* __restrict__ b_ih,          // (2,96)
    const float* __restrict__ b_hh,          // (2,96)
    unsigned short* __restrict__ out2,       // (B,T,64) bf16
    int b0)
{
    const int bl   = blockIdx.x >> 1;
    const int d    = blockIdx.x & 1;
    const int b    = b0 + bl;
    const int lane = threadIdx.x;
    const int i    = lane & 31;
    const int half = lane >> 5;

    float4 wh[3][4];
    #pragma unroll
    for (int g = 0; g < 3; ++g)
        #pragma unroll
        for (int k = 0; k < 4; ++k)
            wh[g][k] = *(const float4*)(w_hh + (size_t)(d*96 + g*32 + i)*32 + half*16 + k*4);

    const float bxr = b_ih[d*96 + i]      + b_hh[d*96 + i];
    const float bxz = b_ih[d*96 + 32 + i] + b_hh[d*96 + 32 + i];
    const float bxn = b_ih[d*96 + 64 + i];
    const float bhn = b_hh[d*96 + 64 + i];

    __shared__ __align__(16) float h_sh[32];
    if (!half) h_sh[i] = 0.0f;
    float h = 0.0f;

    const size_t xrow = (size_t)(bl*2 + d) * TT;
    unsigned short cr, cz, cn;
    {
        const int tx0 = d ? TT-1 : 0;
        cr = xg[(xrow + tx0)*96 + i];
        cz = xg[(xrow + tx0)*96 + 32 + i];
        cn = xg[(xrow + tx0)*96 + 64 + i];
    }

    for (int t = 0; t < TT; ++t) {
        const int tx = d ? (TT-1-t) : t;
        unsigned short nr = cr, nz = cz, nn = cn;
        if (t+1 < TT) {
            const int tx1 = d ? (TT-2-t) : (t+1);
            nr = xg[(xrow + tx1)*96 + i];
            nz = xg[(xrow + tx1)*96 + 32 + i];
            nn = xg[(xrow + tx1)*96 + 64 + i];
        }
        float hr_ = 0.f, hz_ = 0.f, hn_ = 0.f;
        #pragma unroll
        for (int k = 0; k < 4; ++k) {
            const float4 hv = *(const float4*)&h_sh[half*16 + k*4];  // broadcast
            hr_ += hv.x*wh[0][k].x + hv.y*wh[0][k].y + hv.z*wh[0][k].z + hv.w*wh[0][k].w;
            hz_ += hv.x*wh[1][k].x + hv.y*wh[1][k].y + hv.z*wh[1][k].z + hv.w*wh[1][k].w;
            hn_ += hv.x*wh[2][k].x + hv.y*wh[2][k].y + hv.z*wh[2][k].z + hv.w*wh[2][k].w;
        }
        hr_ += __shfl_xor(hr_, 32, 64);
        hz_ += __shfl_xor(hz_, 32, 64);
        hn_ += __shfl_xor(hn_, 32, 64);

        const float r = sigmoidf_(hr_ + bf2f(cr) + bxr);
        const float z = sigmoidf_(hz_ + bf2f(cz) + bxz);
        const float n = tanhf_(bf2f(cn) + bxn + r*(hn_ + bhn));
        h = n + z*(h - n);
        if (!half) {
            h_sh[i] = h;
            out2[((size_t)b*TT + tx)*64 + d*32 + i] = f2bf(h);
        }
        cr = nr; cz = nz; cn = nn;
    }
}

// Attention pooling + FC + sigmoid (bf16 out2 input). One block per b.
__global__ __launch_bounds__(256) void attn_fc(
    const unsigned short* __restrict__ out2, // (B,T,64) bf16
    const float* __restrict__ attn_w, const float* __restrict__ attn_b,
    const float* __restrict__ fc_w,   const float* __restrict__ fc_b,
    float* __restrict__ out)
{
    const int b    = blockIdx.x;
    const int tid  = threadIdx.x;
    const int wave = tid >> 6;
    const int lane = tid & 63;

    __shared__ float logit_sh[TT];
    __shared__ float red_sh[4];
    __shared__ float ctx_sh[4][64];

    const float aw = attn_w[lane];
    const float ab = attn_b[0];

    for (int t = wave; t < TT; t += 4) {
        float v = bf2f(out2[((size_t)b*TT + t)*64 + lane]) * aw;
        #pragma unroll
        for (int off = 32; off > 0; off >>= 1) v += __shfl_xor(v, off, 64);
        if (lane == 0) logit_sh[t] = v + ab;
    }
    __syncthreads();

    float m = -INFINITY;
    for (int t = tid; t < TT; t += 256) m = fmaxf(m, logit_sh[t]);
    #pragma unroll
    for (int off = 32; off > 0; off >>= 1) m = fmaxf(m, __shfl_xor(m, off, 64));
    if (lane == 0) red_sh[wave] = m;
    __syncthreads();
    m = fmaxf(fmaxf(red_sh[0], red_sh[1]), fmaxf(red_sh[2], red_sh[3]));
    __syncthreads();
    float s = 0.0f;
    for (int t = tid; t < TT; t += 256) {
        const float e = __expf(logit_sh[t] - m);
        logit_sh[t] = e;
        s += e;
    }
    #pragma unroll
    for (int off = 32; off > 0; off >>= 1) s += __shfl_xor(s, off, 64);
    if (lane == 0) red_sh[wave] = s;
    __syncthreads();
    s = red_sh[0] + red_sh[1] + red_sh[2] + red_sh[3];
    const float inv_s = 1.0f / s;

    float acc = 0.0f;
    for (int t = wave; t < TT; t += 4)
        acc += logit_sh[t] * bf2f(out2[((size_t)b*TT + t)*64 + lane]);
    ctx_sh[wave][lane] = acc;
    __syncthreads();
    if (wave == 0) {
        const float c = (ctx_sh[0][lane] + ctx_sh[1][lane] +
                         ctx_sh[2][lane] + ctx_sh[3][lane]) * inv_s;
        float v = c * fc_w[lane];
        #pragma unroll
        for (int off = 32; off > 0; off >>= 1) v += __shfl_xor(v, off, 64);
        if (lane == 0) out[b] = sigmoidf_(v + fc_b[0]);
    }
}

extern "C" void kernel_launch(void* const* d_in, const int* in_sizes, int n_in,
                              void* d_out, int out_size, void* d_ws, size_t ws_size,
                              hipStream_t stream) {
    (void)in_sizes; (void)n_in; (void)out_size; (void)ws_size;
    const float* x      = (const float*)d_in[0];
    const float* w_ih0  = (const float*)d_in[1];
    const float* w_hh0  = (const float*)d_in[2];
    const float* b_ih0  = (const float*)d_in[3];
    const float* b_hh0  = (const float*)d_in[4];
    const float* w_ih1  = (const float*)d_in[5];
    const float* w_hh1  = (const float*)d_in[6];
    const float* b_ih1  = (const float*)d_in[7];
    const float* b_hh1  = (const float*)d_in[8];
    const float* attn_w = (const float*)d_in[9];
    const float* attn_b = (const float*)d_in[10];
    const float* fc_w   = (const float*)d_in[11];
    const float* fc_b   = (const float*)d_in[12];
    float* out = (float*)d_out;

    // ws: h1 67.1MB | xg chunk 100.7MB | out2 67.1MB | wbf 24KB  = 224 MiB
    unsigned short* h1  = (unsigned short*)d_ws;
    unsigned short* xgc = (unsigned short*)((char*)d_ws + 67108864);
    unsigned short* o2  = (unsigned short*)((char*)d_ws + 167772160);
    unsigned short* wbf = (unsigned short*)((char*)d_ws + 234881024);

    wcvt<<<48, 256, 0, stream>>>(w_ih1, wbf, 2*96*64);
    gru_l0<<<BB*2, 64, 0, stream>>>(x, w_ih0, w_hh0, b_ih0, b_hh0, h1);

    xg1_pass<<<BC*TT/16, 64, 0, stream>>>(h1, wbf, xgc, 0);
    gru_l1<<<BC*2, 64, 0, stream>>>(xgc, w_hh1, b_ih1, b_hh1, o2, 0);
    xg1_pass<<<BC*TT/16, 64, 0, stream>>>(h1, wbf, xgc, BC);
    gru_l1<<<BC*2, 64, 0, stream>>>(xgc, w_hh1, b_ih1, b_hh1, o2, BC);

    attn_fc<<<BB, 256, 0, stream>>>(o2, attn_w, attn_b, fc_w, fc_b, out);
}

// Round 11
// 1222.997 us; speedup vs baseline: 1.0204x; 1.0204x over previous
//
#include <hip/hip_runtime.h>
#include <math.h>

#define BB 1024
#define TT 512

typedef __attribute__((ext_vector_type(8))) short  short8;
typedef __attribute__((ext_vector_type(4))) float  floatx4;

__device__ __forceinline__ float fast_rcp(float x){ return __builtin_amdgcn_rcpf(x); }
__device__ __forceinline__ float sigmoidf_(float x){ return fast_rcp(1.0f + __expf(-x)); }
__device__ __forceinline__ float tanhf_(float x){
    float t = __expf(2.0f * x);
    return 1.0f - 2.0f * fast_rcp(t + 1.0f);
}
__device__ __forceinline__ unsigned short f2bf(float f){
    unsigned u = __builtin_bit_cast(unsigned, f);
    u += 0x7fffu + ((u >> 16) & 1u);
    return (unsigned short)(u >> 16);
}
__device__ __forceinline__ float bf2f(unsigned short u){
    return __builtin_bit_cast(float, ((unsigned)u) << 16);
}

// ---- AGPR pinning -----------------------------------------------------------
// The allocator remats invariant global loads into the t-loop at ANY pressure
// target (R4-R10: VGPR 56-104 + in-loop reloads / 16 GB overfetch), and
// volatile converts remat to scratch spill (R6/R8). Escape hatch: park the
// weights in the (otherwise idle) AGPR file. The volatile "=a" asm cannot be
// rematerialized or sunk; per-use v_accvgpr_read costs 2 cyc on the VALU pipe
// with zero memory traffic.
__device__ __forceinline__ void apin(float &a, float x){
    asm volatile("v_accvgpr_write_b32 %0, %1" : "=a"(a) : "v"(x));
}
__device__ __forceinline__ float aget(float &a){
    float r;
    asm volatile("v_accvgpr_read_b32 %0, %1" : "=v"(r) : "a"(a));
    return r;
}

// ---------------------------------------------------------------------------
// Layer 0 recurrence, fused tiny projection. 1 wave = one (b,d) sequence.
// lane = i + 32*half; recurrent dot k-split; wh (48) + wi (8) + bias (4)
// pinned in AGPRs.
// ---------------------------------------------------------------------------
__global__ __launch_bounds__(64, 2) void gru_l0(
    const float* __restrict__ x,      // (B,T,4)
    const float* __restrict__ w_ih,   // (2,96,4)
    const float* __restrict__ w_hh,   // (2,96,32)
    const float* __restrict__ b_ih,   // (2,96)
    const float* __restrict__ b_hh,   // (2,96)
    unsigned short* __restrict__ h1)  // (B,T,64) bf16
{
    const int b    = blockIdx.x >> 1;
    const int d    = blockIdx.x & 1;
    const int lane = threadIdx.x;
    const int i    = lane & 31;
    const int half = lane >> 5;

    float wh[48];   // [g*16 + k], k in this half's range
    #pragma unroll
    for (int g = 0; g < 3; ++g)
        #pragma unroll
        for (int k4 = 0; k4 < 4; ++k4){
            const float4 v = *(const float4*)(w_hh + (size_t)(d*96 + g*32 + i)*32 + half*16 + k4*4);
            apin(wh[g*16+k4*4+0], v.x); apin(wh[g*16+k4*4+1], v.y);
            apin(wh[g*16+k4*4+2], v.z); apin(wh[g*16+k4*4+3], v.w);
        }
    float wiA[4], wiB[4];
    {
        const float4 a = *(const float4*)(w_ih + (size_t)(d*96 + (half ? 64 : 0) + i)*4);
        apin(wiA[0], a.x); apin(wiA[1], a.y); apin(wiA[2], a.z); apin(wiA[3], a.w);
        float4 bv = {0.f,0.f,0.f,0.f};
        if (!half) bv = *(const float4*)(w_ih + (size_t)(d*96 + 32 + i)*4);
        apin(wiB[0], bv.x); apin(wiB[1], bv.y); apin(wiB[2], bv.z); apin(wiB[3], bv.w);
    }
    float bxr, bxz, bxn, bhn;
    apin(bxr, b_ih[d*96 + i]      + b_hh[d*96 + i]);
    apin(bxz, b_ih[d*96 + 32 + i] + b_hh[d*96 + 32 + i]);
    apin(bxn, b_ih[d*96 + 64 + i]);
    apin(bhn, b_hh[d*96 + 64 + i]);

    __shared__ __align__(16) float h_sh[32];
    if (!half) h_sh[i] = 0.0f;
    float h = 0.0f;

    const size_t xbase = (size_t)b * TT;
    float4 xc = *(const float4*)(x + (xbase + (d ? TT-1 : 0))*4);

    for (int t = 0; t < TT; ++t) {
        const int tx = d ? (TT-1-t) : t;
        float4 xn4 = xc;
        if (t+1 < TT)
            xn4 = *(const float4*)(x + (xbase + (d ? TT-2-t : t+1))*4);

        const float pA = xc.x*aget(wiA[0]) + xc.y*aget(wiA[1]) + xc.z*aget(wiA[2]) + xc.w*aget(wiA[3]);
        const float pB = xc.x*aget(wiB[0]) + xc.y*aget(wiB[1]) + xc.z*aget(wiB[2]) + xc.w*aget(wiB[3]);

        float hr_ = 0.f, hz_ = 0.f, hn_ = 0.f;
        #pragma unroll
        for (int k4 = 0; k4 < 4; ++k4) {
            const float4 hv = *(const float4*)&h_sh[half*16 + k4*4];  // broadcast
            #pragma unroll
            for (int c = 0; c < 4; ++c) {
                const float hc = (c==0)?hv.x:(c==1)?hv.y:(c==2)?hv.z:hv.w;
                hr_ += hc * aget(wh[     k4*4 + c]);
                hz_ += hc * aget(wh[16 + k4*4 + c]);
                hn_ += hc * aget(wh[32 + k4*4 + c]);
            }
        }
        float sr = hr_ + (half ? 0.f : pA);
        float sz = hz_ + pB;                // pB==0 in half1
        float sn = hn_;
        float sx = half ? pA : 0.f;
        sr += __shfl_xor(sr, 32, 64);
        sz += __shfl_xor(sz, 32, 64);
        sn += __shfl_xor(sn, 32, 64);
        sx += __shfl_xor(sx, 32, 64);

        const float r = sigmoidf_(sr + aget(bxr));
        const float z = sigmoidf_(sz + aget(bxz));
        const float n = tanhf_(sx + aget(bxn) + r*(sn + aget(bhn)));
        h = n + z*(h - n);
        if (!half) {
            h_sh[i] = h;
            h1[(xbase + tx)*64 + d*32 + i] = f2bf(h);
        }
        xc = xn4;
    }
}

// ---------------------------------------------------------------------------
// Layer-1 input projection, parallel MFMA GEMM over full B.
// xg[(b*2+d), t, 96] = h1[b,t,0:64] @ w_ih1[d]^T. Weights converted f32->bf16
// in-kernel (L2-resident after first touch; no workspace needed).
// ---------------------------------------------------------------------------
__global__ __launch_bounds__(64, 1) void xg1_pass(
    const unsigned short* __restrict__ h1,   // (B,T,64) bf16
    const float* __restrict__ w_ih,          // (2,96,64) f32
    unsigned short* __restrict__ xg)         // (B*2,T,96) bf16
{
    const int blk  = blockIdx.x;             // [0, BB*TT/16)
    const int bl   = blk >> 5;               // 32 t-tiles per b
    const int t0   = (blk & 31) << 4;
    const int L    = threadIdx.x;
    const int col  = L & 15;
    const int quad = L >> 4;

    const size_t hrow = ((size_t)bl*TT + t0 + col)*64;
    const short8 a0 = *(const short8*)(&h1[hrow +      quad*8]);
    const short8 a1 = *(const short8*)(&h1[hrow + 32 + quad*8]);

    const floatx4 z4 = {0.f,0.f,0.f,0.f};
    #pragma unroll
    for (int nt = 0; nt < 12; ++nt){
        const int dd = nt / 6, gb = nt % 6;
        const size_t row = (size_t)(dd*96 + gb*16 + col)*64;
        const float4 wf0 = *(const float4*)(w_ih + row +      quad*8);
        const float4 wf1 = *(const float4*)(w_ih + row +      quad*8 + 4);
        const float4 wf2 = *(const float4*)(w_ih + row + 32 + quad*8);
        const float4 wf3 = *(const float4*)(w_ih + row + 32 + quad*8 + 4);
        short8 w0, w1;
        w0[0]=f2bf(wf0.x); w0[1]=f2bf(wf0.y); w0[2]=f2bf(wf0.z); w0[3]=f2bf(wf0.w);
        w0[4]=f2bf(wf1.x); w0[5]=f2bf(wf1.y); w0[6]=f2bf(wf1.z); w0[7]=f2bf(wf1.w);
        w1[0]=f2bf(wf2.x); w1[1]=f2bf(wf2.y); w1[2]=f2bf(wf2.z); w1[3]=f2bf(wf2.w);
        w1[4]=f2bf(wf3.x); w1[5]=f2bf(wf3.y); w1[6]=f2bf(wf3.z); w1[7]=f2bf(wf3.w);
        floatx4 acc = __builtin_amdgcn_mfma_f32_16x16x32_bf16(a0, w0, z4, 0, 0, 0);
        acc         = __builtin_amdgcn_mfma_f32_16x16x32_bf16(a1, w1, acc, 0, 0, 0);
        #pragma unroll
        for (int reg = 0; reg < 4; ++reg)
            xg[((size_t)(bl*2 + dd)*TT + t0 + quad*4 + reg)*96 + gb*16 + col] = f2bf(acc[reg]);
    }
}

// ---------------------------------------------------------------------------
// Layer 1 recurrence: projection from precomputed xg; wh (48) + bias (4)
// pinned in AGPRs.
// ---------------------------------------------------------------------------
__global__ __launch_bounds__(64, 2) void gru_l1(
    const unsigned short* __restrict__ xg,   // (B*2,T,96) bf16
    const float* __restrict__ w_hh,          // (2,96,32)
    const float* __restrict__ b_ih,          // (2,96)
    const float* __restrict__ b_hh,          // (2,96)
    unsigned short* __restrict__ out2)       // (B,T,64) bf16
{
    const int b    = blockIdx.x >> 1;
    const int d    = blockIdx.x & 1;
    const int lane = threadIdx.x;
    const int i    = lane & 31;
    const int half = lane >> 5;

    float wh[48];
    #pragma unroll
    for (int g = 0; g < 3; ++g)
        #pragma unroll
        for (int k4 = 0; k4 < 4; ++k4){
            const float4 v = *(const float4*)(w_hh + (size_t)(d*96 + g*32 + i)*32 + half*16 + k4*4);
            apin(wh[g*16+k4*4+0], v.x); apin(wh[g*16+k4*4+1], v.y);
            apin(wh[g*16+k4*4+2], v.z); apin(wh[g*16+k4*4+3], v.w);
        }
    float bxr, bxz, bxn, bhn;
    apin(bxr, b_ih[d*96 + i]      + b_hh[d*96 + i]);
    apin(bxz, b_ih[d*96 + 32 + i] + b_hh[d*96 + 32 + i]);
    apin(bxn, b_ih[d*96 + 64 + i]);
    apin(bhn, b_hh[d*96 + 64 + i]);

    __shared__ __align__(16) float h_sh[32];
    if (!half) h_sh[i] = 0.0f;
    float h = 0.0f;

    const size_t xrow = (size_t)(b*2 + d) * TT;
    unsigned short cr, cz, cn;
    {
        const int tx0 = d ? TT-1 : 0;
        cr = xg[(xrow + tx0)*96 + i];
        cz = xg[(xrow + tx0)*96 + 32 + i];
        cn = xg[(xrow + tx0)*96 + 64 + i];
    }

    for (int t = 0; t < TT; ++t) {
        const int tx = d ? (TT-1-t) : t;
        unsigned short nr = cr, nz = cz, nn = cn;
        if (t+1 < TT) {
            const int tx1 = d ? (TT-2-t) : (t+1);
            nr = xg[(xrow + tx1)*96 + i];
            nz = xg[(xrow + tx1)*96 + 32 + i];
            nn = xg[(xrow + tx1)*96 + 64 + i];
        }
        float hr_ = 0.f, hz_ = 0.f, hn_ = 0.f;
        #pragma unroll
        for (int k4 = 0; k4 < 4; ++k4) {
            const float4 hv = *(const float4*)&h_sh[half*16 + k4*4];  // broadcast
            #pragma unroll
            for (int c = 0; c < 4; ++c) {
                const float hc = (c==0)?hv.x:(c==1)?hv.y:(c==2)?hv.z:hv.w;
                hr_ += hc * aget(wh[     k4*4 + c]);
                hz_ += hc * aget(wh[16 + k4*4 + c]);
                hn_ += hc * aget(wh[32 + k4*4 + c]);
            }
        }
        hr_ += __shfl_xor(hr_, 32, 64);
        hz_ += __shfl_xor(hz_, 32, 64);
        hn_ += __shfl_xor(hn_, 32, 64);

        const float r = sigmoidf_(hr_ + bf2f(cr) + aget(bxr));
        const float z = sigmoidf_(hz_ + bf2f(cz) + aget(bxz));
        const float n = tanhf_(bf2f(cn) + aget(bxn) + r*(hn_ + aget(bhn)));
        h = n + z*(h - n);
        if (!half) {
            h_sh[i] = h;
            out2[((size_t)b*TT + tx)*64 + d*32 + i] = f2bf(h);
        }
        cr = nr; cz = nz; cn = nn;
    }
}

// Attention pooling + FC + sigmoid (bf16 out2 input). One block per b.
__global__ __launch_bounds__(256) void attn_fc(
    const unsigned short* __restrict__ out2, // (B,T,64) bf16
    const float* __restrict__ attn_w, const float* __restrict__ attn_b,
    const float* __restrict__ fc_w,   const float* __restrict__ fc_b,
    float* __restrict__ out)
{
    const int b    = blockIdx.x;
    const int tid  = threadIdx.x;
    const int wave = tid >> 6;
    const int lane = tid & 63;

    __shared__ float logit_sh[TT];
    __shared__ float red_sh[4];
    __shared__ float ctx_sh[4][64];

    const float aw = attn_w[lane];
    const float ab = attn_b[0];

    for (int t = wave; t < TT; t += 4) {
        float v = bf2f(out2[((size_t)b*TT + t)*64 + lane]) * aw;
        #pragma unroll
        for (int off = 32; off > 0; off >>= 1) v += __shfl_xor(v, off, 64);
        if (lane == 0) logit_sh[t] = v + ab;
    }
    __syncthreads();

    float m = -INFINITY;
    for (int t = tid; t < TT; t += 256) m = fmaxf(m, logit_sh[t]);
    #pragma unroll
    for (int off = 32; off > 0; off >>= 1) m = fmaxf(m, __shfl_xor(m, off, 64));
    if (lane == 0) red_sh[wave] = m;
    __syncthreads();
    m = fmaxf(fmaxf(red_sh[0], red_sh[1]), fmaxf(red_sh[2], red_sh[3]));
    __syncthreads();
    float s = 0.0f;
    for (int t = tid; t < TT; t += 256) {
        const float e = __expf(logit_sh[t] - m);
        logit_sh[t] = e;
        s += e;
    }
    #pragma unroll
    for (int off = 32; off > 0; off >>= 1) s += __shfl_xor(s, off, 64);
    if (lane == 0) red_sh[wave] = s;
    __syncthreads();
    s = red_sh[0] + red_sh[1] + red_sh[2] + red_sh[3];
    const float inv_s = 1.0f / s;

    float acc = 0.0f;
    for (int t = wave; t < TT; t += 4)
        acc += logit_sh[t] * bf2f(out2[((size_t)b*TT + t)*64 + lane]);
    ctx_sh[wave][lane] = acc;
    __syncthreads();
    if (wave == 0) {
        const float c = (ctx_sh[0][lane] + ctx_sh[1][lane] +
                         ctx_sh[2][lane] + ctx_sh[3][lane]) * inv_s;
        float v = c * fc_w[lane];
        #pragma unroll
        for (int off = 32; off > 0; off >>= 1) v += __shfl_xor(v, off, 64);
        if (lane == 0) out[b] = sigmoidf_(v + fc_b[0]);
    }
}

extern "C" void kernel_launch(void* const* d_in, const int* in_sizes, int n_in,
                              void* d_out, int out_size, void* d_ws, size_t ws_size,
                              hipStream_t stream) {
    (void)in_sizes; (void)n_in; (void)out_size; (void)ws_size;
    const float* x      = (const float*)d_in[0];
    const float* w_ih0  = (const float*)d_in[1];
    const float* w_hh0  = (const float*)d_in[2];
    const float* b_ih0  = (const float*)d_in[3];
    const float* b_hh0  = (const float*)d_in[4];
    const float* w_ih1  = (const float*)d_in[5];
    const float* w_hh1  = (const float*)d_in[6];
    const float* b_ih1  = (const float*)d_in[7];
    const float* b_hh1  = (const float*)d_in[8];
    const float* attn_w = (const float*)d_in[9];
    const float* attn_b = (const float*)d_in[10];
    const float* fc_w   = (const float*)d_in[11];
    const float* fc_b   = (const float*)d_in[12];
    float* out = (float*)d_out;

    // ws: [0,64MiB) h1 (bf16) -> later reused as out2 | [64MiB,256MiB) xg (bf16)
    unsigned short* h1 = (unsigned short*)d_ws;                      // 67.1 MB
    unsigned short* xg = (unsigned short*)((char*)d_ws + 67108864);  // 201.3 MB
    unsigned short* o2 = h1;   // h1 dead after xg1_pass

    gru_l0<<<BB*2, 64, 0, stream>>>(x, w_ih0, w_hh0, b_ih0, b_hh0, h1);
    xg1_pass<<<BB*TT/16, 64, 0, stream>>>(h1, w_ih1, xg);
    gru_l1<<<BB*2, 64, 0, stream>>>(xg, w_hh1, b_ih1, b_hh1, o2);
    attn_fc<<<BB, 256, 0, stream>>>(o2, attn_w, attn_b, fc_w, fc_b, out);
}

// Round 13
// 796.690 us; speedup vs baseline: 1.5663x; 1.5351x over previous
//
#include <hip/hip_runtime.h>
#include <math.h>

#define BB 1024
#define TT 512

typedef __attribute__((ext_vector_type(8))) short  short8;
typedef __attribute__((ext_vector_type(4))) float  floatx4;

__device__ __forceinline__ float fast_rcp(float x){ return __builtin_amdgcn_rcpf(x); }
__device__ __forceinline__ float sigmoidf_(float x){ return fast_rcp(1.0f + __expf(-x)); }
__device__ __forceinline__ float tanhf_(float x){
    float t = __expf(2.0f * x);
    return 1.0f - 2.0f * fast_rcp(t + 1.0f);
}
__device__ __forceinline__ unsigned short f2bf(float f){
    unsigned u = __builtin_bit_cast(unsigned, f);
    u += 0x7fffu + ((u >> 16) & 1u);
    return (unsigned short)(u >> 16);
}
__device__ __forceinline__ float bf2f(unsigned short u){
    return __builtin_bit_cast(float, ((unsigned)u) << 16);
}

// ---------------------------------------------------------------------------
// MFMA-batched biGRU recurrence, i-half-split across 2 waves.
// Block = 128 thr = 2 waves = one 16-sequence tile (one (batch16, dir) pair).
// Wave wid owns gate-tiles {r,z,n} for i in [wid*16, wid*16+16): complete
// gate triples live IN-LANE (D-layout: col=lane&15 = gate column within the
// 16-wide tile, row=quad*4+reg = batch). 4 triples/lane -> 12 trans insts
// per wave-step (R9's single-wave version had 24). h: f32 master in regs;
// bf16 copy in a DOUBLE-BUFFERED LDS tile (write h_t to buf[(t+1)&1], read
// h_{t-1} from buf[t&1]) -> exactly one __syncthreads per step.
// h1 store trick: the A-fragment read at step t IS h_{t-1} in store layout ->
// wave0 stores it; no extra ds_read.
// ---------------------------------------------------------------------------
__global__ __launch_bounds__(128, 1) void gru_l0(
    const float* __restrict__ x,      // (B,T,4) f32
    const float* __restrict__ w_ih,   // (2,96,4)
    const float* __restrict__ w_hh,   // (2,96,32)
    const float* __restrict__ b_ih,   // (2,96)
    const float* __restrict__ b_hh,   // (2,96)
    unsigned short* __restrict__ h1)  // (B,T,64) bf16
{
    const int tile = blockIdx.x;      // 0..127
    const int bt   = tile >> 1;
    const int d    = tile & 1;
    const int b0   = bt * 16;
    const int tid  = threadIdx.x;
    const int wid  = tid >> 6;        // i-half this wave owns
    const int L    = tid & 63;
    const int col  = L & 15;
    const int quad = L >> 4;

    // B-fragments: B[n=col][k=quad*8+j]
    short8 bhh[3], bih[3];
    #pragma unroll
    for (int g = 0; g < 3; ++g){
        const int row = d*96 + g*32 + wid*16 + col;
        short8 f;
        #pragma unroll
        for (int j = 0; j < 8; ++j) f[j] = f2bf(w_hh[(size_t)row*32 + quad*8 + j]);
        bhh[g] = f;
        short8 fi = {0,0,0,0,0,0,0,0};
        if (quad == 0){
            #pragma unroll
            for (int j = 0; j < 4; ++j) fi[j] = f2bf(w_ih[(size_t)row*4 + j]);
        }
        bih[g] = fi;
    }
    const int gr = d*96 + wid*16 + col;
    const float br  = b_ih[gr]      + b_hh[gr];
    const float bz  = b_ih[gr + 32] + b_hh[gr + 32];
    const float bni = b_ih[gr + 64];
    const float bhn = b_hh[gr + 64];

    __shared__ unsigned short hsh[2][16*40];
    for (int k = tid; k < 16*40; k += 128) hsh[0][k] = 0;
    float hr[4] = {0.f, 0.f, 0.f, 0.f};
    __syncthreads();

    const size_t xrow = (size_t)(b0 + col) * TT;
    float4 xc = {0,0,0,0}, xn1 = {0,0,0,0};
    if (quad == 0){
        xc  = *(const float4*)(x + (xrow + (d ? TT-1 : 0))*4);
        xn1 = *(const float4*)(x + (xrow + (d ? TT-2 : 1))*4);
    }

    const floatx4 z4 = {0.f,0.f,0.f,0.f};
    for (int t = 0; t < TT; ++t){
        const int rb = t & 1, wb = rb ^ 1;
        const short8 ah = *(const short8*)(&hsh[rb][col*40 + quad*8]);  // = h_{t-1}
        short8 ax = {0,0,0,0,0,0,0,0};
        if (quad == 0){ ax[0]=f2bf(xc.x); ax[1]=f2bf(xc.y); ax[2]=f2bf(xc.z); ax[3]=f2bf(xc.w); }

        floatx4 xg[3], hg[3];
        #pragma unroll
        for (int g = 0; g < 3; ++g)
            xg[g] = __builtin_amdgcn_mfma_f32_16x16x32_bf16(ax, bih[g], z4, 0, 0, 0);
        #pragma unroll
        for (int g = 0; g < 3; ++g)
            hg[g] = __builtin_amdgcn_mfma_f32_16x16x32_bf16(ah, bhh[g], z4, 0, 0, 0);

        // store h_{t-1} (== ah, already in store layout) — wave0 only
        if (wid == 0 && t > 0){
            const int txp = d ? (TT - t) : (t - 1);
            *(short8*)(&h1[((size_t)(b0 + col)*TT + txp)*64 + d*32 + quad*8]) = ah;
        }
        // prefetch x for t+2
        float4 xn2 = xn1;
        if (quad == 0 && t + 2 < TT)
            xn2 = *(const float4*)(x + (xrow + (d ? TT-3-t : t+2))*4);

        #pragma unroll
        for (int r4 = 0; r4 < 4; ++r4){
            const float rg = sigmoidf_(xg[0][r4] + hg[0][r4] + br);
            const float zg = sigmoidf_(xg[1][r4] + hg[1][r4] + bz);
            const float ng = tanhf_(xg[2][r4] + bni + rg*(hg[2][r4] + bhn));
            hr[r4] = ng + zg*(hr[r4] - ng);
            hsh[wb][(quad*4 + r4)*40 + wid*16 + col] = f2bf(hr[r4]);
        }
        __syncthreads();
        xc = xn1; xn1 = xn2;
    }
    // epilogue: h_{TT-1} sits in hsh[TT & 1]
    if (wid == 0){
        const short8 ah = *(const short8*)(&hsh[TT & 1][col*40 + quad*8]);
        const int txl = d ? 0 : TT-1;
        *(short8*)(&h1[((size_t)(b0 + col)*TT + txl)*64 + d*32 + quad*8]) = ah;
    }
}

// ---------------------------------------------------------------------------
// Layer 1: same structure; projection fused as 6 xg MFMAs (K=64 in 2 chunks)
// reading bf16 h1 rows (2-step register prefetch covers HBM latency).
// ---------------------------------------------------------------------------
__global__ __launch_bounds__(128, 1) void gru_l1(
    const unsigned short* __restrict__ h1,   // (B,T,64) bf16
    const float* __restrict__ w_ih,   // (2,96,64)
    const float* __restrict__ w_hh,   // (2,96,32)
    const float* __restrict__ b_ih,   // (2,96)
    const float* __restrict__ b_hh,   // (2,96)
    unsigned short* __restrict__ out2) // (B,T,64) bf16
{
    const int tile = blockIdx.x;
    const int bt   = tile >> 1;
    const int d    = tile & 1;
    const int b0   = bt * 16;
    const int tid  = threadIdx.x;
    const int wid  = tid >> 6;
    const int L    = tid & 63;
    const int col  = L & 15;
    const int quad = L >> 4;

    short8 bhh[3], bi0[3], bi1[3];
    #pragma unroll
    for (int g = 0; g < 3; ++g){
        const int row = d*96 + g*32 + wid*16 + col;
        short8 f, g0, g1;
        #pragma unroll
        for (int j = 0; j < 8; ++j){
            f[j]  = f2bf(w_hh[(size_t)row*32 + quad*8 + j]);
            g0[j] = f2bf(w_ih[(size_t)row*64 +      quad*8 + j]);
            g1[j] = f2bf(w_ih[(size_t)row*64 + 32 + quad*8 + j]);
        }
        bhh[g] = f; bi0[g] = g0; bi1[g] = g1;
    }
    const int gr = d*96 + wid*16 + col;
    const float br  = b_ih[gr]      + b_hh[gr];
    const float bz  = b_ih[gr + 32] + b_hh[gr + 32];
    const float bni = b_ih[gr + 64];
    const float bhn = b_hh[gr + 64];

    __shared__ unsigned short hsh[2][16*40];
    for (int k = tid; k < 16*40; k += 128) hsh[0][k] = 0;
    float hr[4] = {0.f, 0.f, 0.f, 0.f};
    __syncthreads();

    const size_t arow = (size_t)(b0 + col) * TT;
    short8 a0c, a1c, a0n, a1n;
    {
        const int tx0 = d ? TT-1 : 0;
        a0c = *(const short8*)(&h1[(arow + tx0)*64 +      quad*8]);
        a1c = *(const short8*)(&h1[(arow + tx0)*64 + 32 + quad*8]);
        const int tx1 = d ? TT-2 : 1;
        a0n = *(const short8*)(&h1[(arow + tx1)*64 +      quad*8]);
        a1n = *(const short8*)(&h1[(arow + tx1)*64 + 32 + quad*8]);
    }

    const floatx4 z4 = {0.f,0.f,0.f,0.f};
    for (int t = 0; t < TT; ++t){
        const int rb = t & 1, wb = rb ^ 1;
        const short8 ah = *(const short8*)(&hsh[rb][col*40 + quad*8]);  // h_{t-1}

        floatx4 xg[3], hg[3];
        #pragma unroll
        for (int g = 0; g < 3; ++g){
            floatx4 acc = __builtin_amdgcn_mfma_f32_16x16x32_bf16(a0c, bi0[g], z4, 0, 0, 0);
            xg[g]       = __builtin_amdgcn_mfma_f32_16x16x32_bf16(a1c, bi1[g], acc, 0, 0, 0);
        }
        #pragma unroll
        for (int g = 0; g < 3; ++g)
            hg[g] = __builtin_amdgcn_mfma_f32_16x16x32_bf16(ah, bhh[g], z4, 0, 0, 0);

        if (wid == 0 && t > 0){
            const int txp = d ? (TT - t) : (t - 1);
            *(short8*)(&out2[((size_t)(b0 + col)*TT + txp)*64 + d*32 + quad*8]) = ah;
        }
        // prefetch h1 row for t+2
        short8 a02 = a0n, a12 = a1n;
        if (t + 2 < TT){
            const int tx2 = d ? (TT-3-t) : (t+2);
            a02 = *(const short8*)(&h1[(arow + tx2)*64 +      quad*8]);
            a12 = *(const short8*)(&h1[(arow + tx2)*64 + 32 + quad*8]);
        }

        #pragma unroll
        for (int r4 = 0; r4 < 4; ++r4){
            const float rg = sigmoidf_(xg[0][r4] + hg[0][r4] + br);
            const float zg = sigmoidf_(xg[1][r4] + hg[1][r4] + bz);
            const float ng = tanhf_(xg[2][r4] + bni + rg*(hg[2][r4] + bhn));
            hr[r4] = ng + zg*(hr[r4] - ng);
            hsh[wb][(quad*4 + r4)*40 + wid*16 + col] = f2bf(hr[r4]);
        }
        __syncthreads();
        a0c = a0n; a1c = a1n; a0n = a02; a1n = a12;
    }
    if (wid == 0){
        const short8 ah = *(const short8*)(&hsh[TT & 1][col*40 + quad*8]);
        const int txl = d ? 0 : TT-1;
        *(short8*)(&out2[((size_t)(b0 + col)*TT + txl)*64 + d*32 + quad*8]) = ah;
    }
}

// Attention pooling + FC + sigmoid (bf16 out2 input). One block per b.
__global__ __launch_bounds__(256) void attn_fc(
    const unsigned short* __restrict__ out2, // (B,T,64) bf16
    const float* __restrict__ attn_w, const float* __restrict__ attn_b,
    const float* __restrict__ fc_w,   const float* __restrict__ fc_b,
    float* __restrict__ out)
{
    const int b    = blockIdx.x;
    const int tid  = threadIdx.x;
    const int wave = tid >> 6;
    const int lane = tid & 63;

    __shared__ float logit_sh[TT];
    __shared__ float red_sh[4];
    __shared__ float ctx_sh[4][64];

    const float aw = attn_w[lane];
    const float ab = attn_b[0];

    for (int t = wave; t < TT; t += 4) {
        float v = bf2f(out2[((size_t)b*TT + t)*64 + lane]) * aw;
        #pragma unroll
        for (int off = 32; off > 0; off >>= 1) v += __shfl_xor(v, off, 64);
        if (lane == 0) logit_sh[t] = v + ab;
    }
    __syncthreads();

    float m = -INFINITY;
    for (int t = tid; t < TT; t += 256) m = fmaxf(m, logit_sh[t]);
    #pragma unroll
    for (int off = 32; off > 0; off >>= 1) m = fmaxf(m, __shfl_xor(m, off, 64));
    if (lane == 0) red_sh[wave] = m;
    __syncthreads();
    m = fmaxf(fmaxf(red_sh[0], red_sh[1]), fmaxf(red_sh[2], red_sh[3]));
    __syncthreads();
    float s = 0.0f;
    for (int t = tid; t < TT; t += 256) {
        const float e = __expf(logit_sh[t] - m);
        logit_sh[t] = e;
        s += e;
    }
    #pragma unroll
    for (int off = 32; off > 0; off >>= 1) s += __shfl_xor(s, off, 64);
    if (lane == 0) red_sh[wave] = s;
    __syncthreads();
    s = red_sh[0] + red_sh[1] + red_sh[2] + red_sh[3];
    const float inv_s = 1.0f / s;

    float acc = 0.0f;
    for (int t = wave; t < TT; t += 4)
        acc += logit_sh[t] * bf2f(out2[((size_t)b*TT + t)*64 + lane]);
    ctx_sh[wave][lane] = acc;
    __syncthreads();
    if (wave == 0) {
        const float c = (ctx_sh[0][lane] + ctx_sh[1][lane] +
                         ctx_sh[2][lane] + ctx_sh[3][lane]) * inv_s;
        float v = c * fc_w[lane];
        #pragma unroll
        for (int off = 32; off > 0; off >>= 1) v += __shfl_xor(v, off, 64);
        if (lane == 0) out[b] = sigmoidf_(v + fc_b[0]);
    }
}

extern "C" void kernel_launch(void* const* d_in, const int* in_sizes, int n_in,
                              void* d_out, int out_size, void* d_ws, size_t ws_size,
                              hipStream_t stream) {
    (void)in_sizes; (void)n_in; (void)out_size; (void)ws_size;
    const float* x      = (const float*)d_in[0];
    const float* w_ih0  = (const float*)d_in[1];
    const float* w_hh0  = (const float*)d_in[2];
    const float* b_ih0  = (const float*)d_in[3];
    const float* b_hh0  = (const float*)d_in[4];
    const float* w_ih1  = (const float*)d_in[5];
    const float* w_hh1  = (const float*)d_in[6];
    const float* b_ih1  = (const float*)d_in[7];
    const float* b_hh1  = (const float*)d_in[8];
    const float* attn_w = (const float*)d_in[9];
    const float* attn_b = (const float*)d_in[10];
    const float* fc_w   = (const float*)d_in[11];
    const float* fc_b   = (const float*)d_in[12];
    float* out = (float*)d_out;

    unsigned short* h1 = (unsigned short*)d_ws;                        // 67.1 MB bf16
    unsigned short* o2 = (unsigned short*)((char*)d_ws + 134217728);   // 67.1 MB bf16

    gru_l0<<<128, 128, 0, stream>>>(x, w_ih0, w_hh0, b_ih0, b_hh0, h1);
    gru_l1<<<128, 128, 0, stream>>>(h1, w_ih1, w_hh1, b_ih1, b_hh1, o2);
    attn_fc<<<BB, 256, 0, stream>>>(o2, attn_w, attn_b, fc_w, fc_b, out);
}